// Round 10
// baseline (418.947 us; speedup 1.0000x reference)
//
#include <hip/hip_runtime.h>
#include <hip/hip_bf16.h>

typedef float  f32x4 __attribute__((ext_vector_type(4)));
typedef short  s16x8 __attribute__((ext_vector_type(8)));

#define NB   1024
#define SEQ  64
#define DIM  512
#define NH   8
#define SCALE 0.044194173824159216f

// round-half-up f32->bf16: 2 VALU ops
static __device__ __forceinline__ unsigned short f2bf(float f) {
    unsigned u = __builtin_bit_cast(unsigned, f);
    return (unsigned short)((u + 0x8000u) >> 16);
}

static __device__ __forceinline__ f32x4 mma(s16x8 a, s16x8 b, f32x4 c) {
    return __builtin_amdgcn_mfma_f32_16x16x32_bf16(a, b, c, 0, 0, 0);
}

// load 8 consecutive f32, convert to a bf16 frag slice (fallback path)
static __device__ __forceinline__ s16x8 ldcvt(const float* p) {
    float4 v0 = *(const float4*)(p);
    float4 v1 = *(const float4*)(p + 4);
    s16x8 r;
    r[0] = (short)f2bf(v0.x); r[1] = (short)f2bf(v0.y);
    r[2] = (short)f2bf(v0.z); r[3] = (short)f2bf(v0.w);
    r[4] = (short)f2bf(v1.x); r[5] = (short)f2bf(v1.y);
    r[6] = (short)f2bf(v1.z); r[7] = (short)f2bf(v1.w);
    return r;
}

// Pre-kernel: Wq, Wc (f32 [512][512] row-major [k][n]) -> bf16 B-fragment order.
__global__ __launch_bounds__(256) void prep_weights(
    const float* __restrict__ Wq, const float* __restrict__ Wc,
    unsigned short* __restrict__ wf)
{
    int gid  = blockIdx.x * 256 + threadIdx.x;   // 0..65535
    int m    = gid >> 15;
    int tile = (gid >> 10) & 31;
    int ks   = (gid >> 6) & 15;
    int lane = gid & 63;
    const float* W = m ? Wc : Wq;
    int col = tile * 16 + (lane & 15);
    int k0  = ks * 32 + (lane >> 4) * 8;
    unsigned short* dst = wf + (size_t)gid * 8;
#pragma unroll
    for (int j = 0; j < 8; ++j)
        dst[j] = f2bf(W[(size_t)(k0 + j) * DIM + col]);
}

// Pre-kernel: f32 -> bf16 for BOTH activation tensors, row-major preserved.
// dst layout: [m][b][s][d] bf16 (m=0 query, m=1 context). dst lives in d_out's
// storage (134 MB of the 268 MB f32 output buffer): proj reads it, then the
// tail overwrites d_out entirely — lifetimes are stream-ordered and disjoint.
__global__ __launch_bounds__(256) void prep_acts(
    const float* __restrict__ q, const float* __restrict__ c,
    unsigned short* __restrict__ dst)
{
    const size_t HALF = (size_t)NB * SEQ * DIM;
    size_t i = ((size_t)blockIdx.x * 256 + threadIdx.x) * 8;
    const float* src = (i < HALF) ? (q + i) : (c + (i - HALF));
    float4 v0 = *(const float4*)(src);
    float4 v1 = *(const float4*)(src + 4);
    s16x8 r;
    r[0] = (short)f2bf(v0.x); r[1] = (short)f2bf(v0.y);
    r[2] = (short)f2bf(v0.z); r[3] = (short)f2bf(v0.w);
    r[4] = (short)f2bf(v1.x); r[5] = (short)f2bf(v1.y);
    r[6] = (short)f2bf(v1.z); r[7] = (short)f2bf(v1.w);
    *(s16x8*)(dst + i) = r;
}

// ====================== Kernel 1: projections (direct, barrier-free) =======
// One wave = one (b, m, h) 64x64 output tile. A-frags: single 16B loads from
// bf16 acts (L3-resident); B-frags: L2-hot weight frags. NO LDS, NO barriers,
// NO conversion in the load->MFMA chain. Explicit 1-deep pipeline with two
// named reg sets (static indexing, fully unrolled).
// NOTE: plain __launch_bounds__ — a min-waves 2nd arg clamps the unified
// VGPR/AGPR budget below the 64-AGPR accumulator -> scratch spills
// (proved rounds 2 and 7: WRITE_SIZE +100 MB both times).
__global__ __launch_bounds__(256) void proj_direct(
    const unsigned short* __restrict__ acts,   // [2][NB][SEQ][DIM] bf16
    const float* __restrict__ bq,
    const float* __restrict__ bc,
    const unsigned short* __restrict__ wf,
    unsigned short* __restrict__ pp)
{
    const int lane = threadIdx.x & 63;
    const int wv   = threadIdx.x >> 6;
    const int l15  = lane & 15;
    const int l4   = lane >> 4;

    // XCD swizzle (grid 4096, %8==0 bijective): orig-consecutive blocks share
    // an XCD; the 8 waves touching one (b,m) act tile are 2 adjacent blocks.
    const int i    = blockIdx.x;
    const int orig = (i & 7) * 512 + (i >> 3);
    const int b    = orig >> 2;
    const int m    = (orig >> 1) & 1;
    const int hq   = orig & 1;
    const int h    = hq * 4 + wv;

    const unsigned short* actw = acts + ((size_t)m * NB + b) * SEQ * DIM;
    const float* bias = m ? bc : bq;
    const unsigned short* wfm = wf + (size_t)m * 262144;

    const f32x4 fz = {0.f, 0.f, 0.f, 0.f};
    f32x4 acc[4][4];
#pragma unroll
    for (int x = 0; x < 4; ++x)
#pragma unroll
        for (int y = 0; y < 4; ++y) acc[x][y] = fz;

    s16x8 afA[4], bfA[4], afB[4], bfB[4];

#define LOADK(KS, AF, BF)                                                      \
    {                                                                          \
        const int k0_ = (KS) * 32 + l4 * 8;                                    \
        _Pragma("unroll")                                                      \
        for (int mt = 0; mt < 4; ++mt)                                         \
            AF[mt] = *(const s16x8*)(actw + (size_t)(mt * 16 + l15) * DIM + k0_); \
        _Pragma("unroll")                                                      \
        for (int nt = 0; nt < 4; ++nt)                                         \
            BF[nt] = *(const s16x8*)(wfm +                                     \
                     ((size_t)((h * 4 + nt) * 16 + (KS)) * 64 + lane) * 8);    \
    }
#define MMAK(AF, BF)                                                           \
    {                                                                          \
        _Pragma("unroll")                                                      \
        for (int mt = 0; mt < 4; ++mt)                                         \
            _Pragma("unroll")                                                  \
            for (int nt = 0; nt < 4; ++nt)                                     \
                acc[mt][nt] = mma(AF[mt], BF[nt], acc[mt][nt]);                \
    }

    LOADK(0, afA, bfA);
#pragma unroll
    for (int ks = 0; ks < 16; ks += 2) {
        if (ks + 1 < 16) LOADK(ks + 1, afB, bfB);
        MMAK(afA, bfA);
        if (ks + 2 < 16) LOADK(ks + 2, afA, bfA);
        MMAK(afB, bfB);
    }
#undef LOADK
#undef MMAK

    unsigned short* dst = pp + (((size_t)m * NB + b) * NH + h) * 4096;
#pragma unroll
    for (int nt = 0; nt < 4; ++nt) {
        float bv = bias[h * 64 + nt * 16 + l15];
#pragma unroll
        for (int mt = 0; mt < 4; ++mt)
#pragma unroll
            for (int r = 0; r < 4; ++r)
                dst[(mt * 16 + l4 * 4 + r) * 64 + nt * 16 + l15] =
                    f2bf(acc[mt][nt][r] + bv);
    }
}

// ====================== Kernel 2: attention tail ======================
// One wave -> one (b,h). cb/qa as direct global frag loads; Qp staged in
// per-wave LDS only for the qb transpose; P1/P2^T reuse the same tile.
__global__ __launch_bounds__(256) void tail_kernel(
    const unsigned short* __restrict__ pp,
    float* __restrict__ out)
{
    __shared__ unsigned short sT[4][SEQ][72];

    const int lane = threadIdx.x & 63;
    const int wv   = threadIdx.x >> 6;
    const int l15  = lane & 15;
    const int l4   = lane >> 4;

    const int i    = blockIdx.x;
    const int orig = (i & 7) * 256 + (i >> 3);
    const int b    = orig >> 1;
    const int half = orig & 1;
    const int h    = half * 4 + wv;

    const unsigned short* qp = pp + ((size_t)b * NH + h) * 4096;
    const unsigned short* cp = pp + (((size_t)NB + b) * NH + h) * 4096;

    const f32x4 fz = {0.f, 0.f, 0.f, 0.f};
    unsigned short (*T)[72] = sT[wv];

    s16x8 cb[4][2], qa[4][2];
#pragma unroll
    for (int nt = 0; nt < 4; ++nt)
#pragma unroll
        for (int ks = 0; ks < 2; ++ks)
            cb[nt][ks] = *(const s16x8*)(cp + (nt * 16 + l15) * 64 + ks * 32 + l4 * 8);
#pragma unroll
    for (int mt = 0; mt < 4; ++mt)
#pragma unroll
        for (int ks = 0; ks < 2; ++ks)
            qa[mt][ks] = *(const s16x8*)(qp + (mt * 16 + l15) * 64 + ks * 32 + l4 * 8);

#pragma unroll
    for (int j = 0; j < 8; ++j) {
        int row = j * 8 + (lane >> 3);
        int col = (lane & 7) * 8;
        *(s16x8*)&T[row][col] = *(const s16x8*)(qp + row * 64 + col);
    }

    s16x8 qb[4][2];
#pragma unroll
    for (int nt = 0; nt < 4; ++nt)
#pragma unroll
        for (int ks = 0; ks < 2; ++ks) {
            s16x8 v;
#pragma unroll
            for (int j = 0; j < 8; ++j)
                v[j] = (short)T[ks * 32 + l4 * 8 + j][nt * 16 + l15];
            qb[nt][ks] = v;
        }

    f32x4 Sc[4][4];
#pragma unroll
    for (int x = 0; x < 4; ++x)
#pragma unroll
        for (int y = 0; y < 4; ++y) Sc[x][y] = fz;
#pragma unroll
    for (int ks = 0; ks < 2; ++ks)
#pragma unroll
        for (int mt = 0; mt < 4; ++mt)
#pragma unroll
            for (int nt = 0; nt < 4; ++nt)
                Sc[mt][nt] = mma(qa[mt][ks], cb[nt][ks], Sc[mt][nt]);

    // softmax over keys (rows): P1 -> T
#pragma unroll
    for (int mt = 0; mt < 4; ++mt)
#pragma unroll
        for (int r = 0; r < 4; ++r) {
            float m = fmaxf(fmaxf(Sc[mt][0][r], Sc[mt][1][r]),
                            fmaxf(Sc[mt][2][r], Sc[mt][3][r]));
            m = fmaxf(m, __shfl_xor(m, 1));
            m = fmaxf(m, __shfl_xor(m, 2));
            m = fmaxf(m, __shfl_xor(m, 4));
            m = fmaxf(m, __shfl_xor(m, 8));
            float e[4], s = 0.f;
#pragma unroll
            for (int nt = 0; nt < 4; ++nt) { e[nt] = __expf(SCALE * (Sc[mt][nt][r] - m)); s += e[nt]; }
            s += __shfl_xor(s, 1);
            s += __shfl_xor(s, 2);
            s += __shfl_xor(s, 4);
            s += __shfl_xor(s, 8);
            float inv = 1.f / s;
            int row = mt * 16 + l4 * 4 + r;
#pragma unroll
            for (int nt = 0; nt < 4; ++nt)
                T[row][nt * 16 + l15] = f2bf(e[nt] * inv);
        }

    s16x8 pa[4][2];
#pragma unroll
    for (int mt = 0; mt < 4; ++mt)
#pragma unroll
        for (int ks = 0; ks < 2; ++ks)
            pa[mt][ks] = *(const s16x8*)&T[mt * 16 + l15][ks * 32 + l4 * 8];

    // softmax over queries (cols): P2^T -> T
#pragma unroll
    for (int nt = 0; nt < 4; ++nt) {
        float m = -1e30f;
#pragma unroll
        for (int mt = 0; mt < 4; ++mt)
#pragma unroll
            for (int r = 0; r < 4; ++r) m = fmaxf(m, Sc[mt][nt][r]);
        m = fmaxf(m, __shfl_xor(m, 16));
        m = fmaxf(m, __shfl_xor(m, 32));
        float ee[4][4], s = 0.f;
#pragma unroll
        for (int mt = 0; mt < 4; ++mt)
#pragma unroll
            for (int r = 0; r < 4; ++r) { ee[mt][r] = __expf(SCALE * (Sc[mt][nt][r] - m)); s += ee[mt][r]; }
        s += __shfl_xor(s, 16);
        s += __shfl_xor(s, 32);
        float inv = 1.f / s;
        int krow = nt * 16 + l15;
#pragma unroll
        for (int mt = 0; mt < 4; ++mt)
#pragma unroll
            for (int r = 0; r < 4; ++r)
                T[krow][mt * 16 + l4 * 4 + r] = f2bf(ee[mt][r] * inv);
    }

    // c_coattn = P1 @ Cp^T
    f32x4 O[4][4];
#pragma unroll
    for (int x = 0; x < 4; ++x)
#pragma unroll
        for (int y = 0; y < 4; ++y) O[x][y] = fz;
#pragma unroll
    for (int ks = 0; ks < 2; ++ks)
#pragma unroll
        for (int mt = 0; mt < 4; ++mt)
#pragma unroll
            for (int nt = 0; nt < 4; ++nt)
                O[mt][nt] = mma(pa[mt][ks], cb[nt][ks], O[mt][nt]);

    float* cO = out;
#pragma unroll
    for (int mt = 0; mt < 4; ++mt)
#pragma unroll
        for (int nt = 0; nt < 4; ++nt)
#pragma unroll
            for (int r = 0; r < 4; ++r) {
                int qrow = mt * 16 + l4 * 4 + r;
                cO[((size_t)b * SEQ + qrow) * (NH * 64) + h * 64 + nt * 16 + l15] = O[mt][nt][r];
            }

    // q_coattn = P2^T @ Qp
    s16x8 p2a[4][2];
#pragma unroll
    for (int mt = 0; mt < 4; ++mt)
#pragma unroll
        for (int ks = 0; ks < 2; ++ks)
            p2a[mt][ks] = *(const s16x8*)&T[mt * 16 + l15][ks * 32 + l4 * 8];

#pragma unroll
    for (int x = 0; x < 4; ++x)
#pragma unroll
        for (int y = 0; y < 4; ++y) O[x][y] = fz;
#pragma unroll
    for (int ks = 0; ks < 2; ++ks)
#pragma unroll
        for (int mt = 0; mt < 4; ++mt)
#pragma unroll
            for (int nt = 0; nt < 4; ++nt)
                O[mt][nt] = mma(p2a[mt][ks], qb[nt][ks], O[mt][nt]);

    float* qO = out + (size_t)NB * SEQ * NH * 64;
#pragma unroll
    for (int mt = 0; mt < 4; ++mt)
#pragma unroll
        for (int nt = 0; nt < 4; ++nt)
#pragma unroll
            for (int r = 0; r < 4; ++r) {
                int krow = mt * 16 + l4 * 4 + r;
                qO[((size_t)b * SEQ + krow) * (NH * 64) + h * 64 + nt * 16 + l15] = O[mt][nt][r];
            }
}

// ====================== Fallback: fused (round-3 style) ======================
__global__ __launch_bounds__(256) void coattn_fused(
    const float* __restrict__ query,
    const float* __restrict__ context,
    const float* __restrict__ bq,
    const float* __restrict__ bc,
    const unsigned short* __restrict__ wf,
    float* __restrict__ out)
{
    __shared__ unsigned short sT[4][SEQ][72];
    const int tid  = threadIdx.x;
    const int lane = tid & 63;
    const int wv   = tid >> 6;
    const int l15  = lane & 15;
    const int l4   = lane >> 4;
    const int B_id = blockIdx.x;
    const int half = (B_id >> 3) & 1;
    const int b    = (B_id & 7) | ((B_id >> 4) << 3);
    const int h    = half * 4 + wv;
    const float* gq = query   + (size_t)b * SEQ * DIM;
    const float* gc = context + (size_t)b * SEQ * DIM;
    const f32x4 fz = {0.f, 0.f, 0.f, 0.f};
    unsigned short (*T)[72] = sT[wv];
    f32x4 acc[4][4];
#pragma unroll
    for (int i = 0; i < 4; ++i)
#pragma unroll
        for (int j = 0; j < 4; ++j) acc[i][j] = fz;
    for (int ks = 0; ks < 16; ++ks) {
        const int k0 = ks * 32 + l4 * 8;
        s16x8 af[4], bf[4];
#pragma unroll
        for (int mt = 0; mt < 4; ++mt)
            af[mt] = ldcvt(gc + (size_t)(mt * 16 + l15) * DIM + k0);
#pragma unroll
        for (int nt = 0; nt < 4; ++nt)
            bf[nt] = *(const s16x8*)(wf + 262144 +
                     ((size_t)((h * 4 + nt) * 16 + ks) * 64 + lane) * 8);
#pragma unroll
        for (int mt = 0; mt < 4; ++mt)
#pragma unroll
            for (int nt = 0; nt < 4; ++nt)
                acc[mt][nt] = mma(af[mt], bf[nt], acc[mt][nt]);
    }
#pragma unroll
    for (int nt = 0; nt < 4; ++nt) {
        float bcv = bc[h * 64 + nt * 16 + l15];
#pragma unroll
        for (int mt = 0; mt < 4; ++mt)
#pragma unroll
            for (int r = 0; r < 4; ++r)
                T[mt * 16 + l4 * 4 + r][nt * 16 + l15] = f2bf(acc[mt][nt][r] + bcv);
    }
    s16x8 cb[4][2];
#pragma unroll
    for (int nt = 0; nt < 4; ++nt)
#pragma unroll
        for (int ks = 0; ks < 2; ++ks)
            cb[nt][ks] = *(const s16x8*)&T[nt * 16 + l15][ks * 32 + l4 * 8];
#pragma unroll
    for (int i = 0; i < 4; ++i)
#pragma unroll
        for (int j = 0; j < 4; ++j) acc[i][j] = fz;
    for (int ks = 0; ks < 16; ++ks) {
        const int k0 = ks * 32 + l4 * 8;
        s16x8 af[4], bf[4];
#pragma unroll
        for (int mt = 0; mt < 4; ++mt)
            af[mt] = ldcvt(gq + (size_t)(mt * 16 + l15) * DIM + k0);
#pragma unroll
        for (int nt = 0; nt < 4; ++nt)
            bf[nt] = *(const s16x8*)(wf +
                     ((size_t)((h * 4 + nt) * 16 + ks) * 64 + lane) * 8);
#pragma unroll
        for (int mt = 0; mt < 4; ++mt)
#pragma unroll
            for (int nt = 0; nt < 4; ++nt)
                acc[mt][nt] = mma(af[mt], bf[nt], acc[mt][nt]);
    }
#pragma unroll
    for (int nt = 0; nt < 4; ++nt) {
        float bqv = bq[h * 64 + nt * 16 + l15];
#pragma unroll
        for (int mt = 0; mt < 4; ++mt)
#pragma unroll
            for (int r = 0; r < 4; ++r)
                T[mt * 16 + l4 * 4 + r][nt * 16 + l15] = f2bf(acc[mt][nt][r] + bqv);
    }
    s16x8 qa[4][2], qb[4][2];
#pragma unroll
    for (int mt = 0; mt < 4; ++mt)
#pragma unroll
        for (int ks = 0; ks < 2; ++ks)
            qa[mt][ks] = *(const s16x8*)&T[mt * 16 + l15][ks * 32 + l4 * 8];
#pragma unroll
    for (int nt = 0; nt < 4; ++nt)
#pragma unroll
        for (int ks = 0; ks < 2; ++ks) {
            s16x8 v;
#pragma unroll
            for (int j = 0; j < 8; ++j)
                v[j] = (short)T[ks * 32 + l4 * 8 + j][nt * 16 + l15];
            qb[nt][ks] = v;
        }
    f32x4 Sc[4][4];
#pragma unroll
    for (int i = 0; i < 4; ++i)
#pragma unroll
        for (int j = 0; j < 4; ++j) Sc[i][j] = fz;
#pragma unroll
    for (int ks = 0; ks < 2; ++ks)
#pragma unroll
        for (int mt = 0; mt < 4; ++mt)
#pragma unroll
            for (int nt = 0; nt < 4; ++nt)
                Sc[mt][nt] = mma(qa[mt][ks], cb[nt][ks], Sc[mt][nt]);
#pragma unroll
    for (int mt = 0; mt < 4; ++mt)
#pragma unroll
        for (int r = 0; r < 4; ++r) {
            float m = fmaxf(fmaxf(Sc[mt][0][r], Sc[mt][1][r]),
                            fmaxf(Sc[mt][2][r], Sc[mt][3][r]));
            m = fmaxf(m, __shfl_xor(m, 1));
            m = fmaxf(m, __shfl_xor(m, 2));
            m = fmaxf(m, __shfl_xor(m, 4));
            m = fmaxf(m, __shfl_xor(m, 8));
            float e[4], s = 0.f;
#pragma unroll
            for (int nt = 0; nt < 4; ++nt) { e[nt] = __expf(SCALE * (Sc[mt][nt][r] - m)); s += e[nt]; }
            s += __shfl_xor(s, 1);
            s += __shfl_xor(s, 2);
            s += __shfl_xor(s, 4);
            s += __shfl_xor(s, 8);
            float inv = 1.f / s;
            int row = mt * 16 + l4 * 4 + r;
#pragma unroll
            for (int nt = 0; nt < 4; ++nt)
                T[row][nt * 16 + l15] = f2bf(e[nt] * inv);
        }
    s16x8 pa[4][2];
#pragma unroll
    for (int mt = 0; mt < 4; ++mt)
#pragma unroll
        for (int ks = 0; ks < 2; ++ks)
            pa[mt][ks] = *(const s16x8*)&T[mt * 16 + l15][ks * 32 + l4 * 8];
#pragma unroll
    for (int nt = 0; nt < 4; ++nt) {
        float m = -1e30f;
#pragma unroll
        for (int mt = 0; mt < 4; ++mt)
#pragma unroll
            for (int r = 0; r < 4; ++r) m = fmaxf(m, Sc[mt][nt][r]);
        m = fmaxf(m, __shfl_xor(m, 16));
        m = fmaxf(m, __shfl_xor(m, 32));
        float ee[4][4], s = 0.f;
#pragma unroll
        for (int mt = 0; mt < 4; ++mt)
#pragma unroll
            for (int r = 0; r < 4; ++r) { ee[mt][r] = __expf(SCALE * (Sc[mt][nt][r] - m)); s += ee[mt][r]; }
        s += __shfl_xor(s, 16);
        s += __shfl_xor(s, 32);
        float inv = 1.f / s;
        int krow = nt * 16 + l15;
#pragma unroll
        for (int mt = 0; mt < 4; ++mt)
#pragma unroll
            for (int r = 0; r < 4; ++r)
                T[krow][mt * 16 + l4 * 4 + r] = f2bf(ee[mt][r] * inv);
    }
    s16x8 p2a[4][2];
#pragma unroll
    for (int mt = 0; mt < 4; ++mt)
#pragma unroll
        for (int ks = 0; ks < 2; ++ks)
            p2a[mt][ks] = *(const s16x8*)&T[mt * 16 + l15][ks * 32 + l4 * 8];
    f32x4 O[4][4];
#pragma unroll
    for (int i = 0; i < 4; ++i)
#pragma unroll
        for (int j = 0; j < 4; ++j) O[i][j] = fz;
#pragma unroll
    for (int ks = 0; ks < 2; ++ks)
#pragma unroll
        for (int mt = 0; mt < 4; ++mt)
#pragma unroll
            for (int nt = 0; nt < 4; ++nt)
                O[mt][nt] = mma(pa[mt][ks], cb[nt][ks], O[mt][nt]);
    float* cO = out;
#pragma unroll
    for (int mt = 0; mt < 4; ++mt)
#pragma unroll
        for (int nt = 0; nt < 4; ++nt)
#pragma unroll
            for (int r = 0; r < 4; ++r) {
                int qrow = mt * 16 + l4 * 4 + r;
                cO[((size_t)b * SEQ + qrow) * (NH * 64) + h * 64 + nt * 16 + l15] = O[mt][nt][r];
            }
#pragma unroll
    for (int i = 0; i < 4; ++i)
#pragma unroll
        for (int j = 0; j < 4; ++j) O[i][j] = fz;
#pragma unroll
    for (int ks = 0; ks < 2; ++ks)
#pragma unroll
        for (int mt = 0; mt < 4; ++mt)
#pragma unroll
            for (int nt = 0; nt < 4; ++nt)
                O[mt][nt] = mma(p2a[mt][ks], qb[nt][ks], O[mt][nt]);
    float* qO = out + (size_t)NB * SEQ * NH * 64;
#pragma unroll
    for (int mt = 0; mt < 4; ++mt)
#pragma unroll
        for (int nt = 0; nt < 4; ++nt)
#pragma unroll
            for (int r = 0; r < 4; ++r) {
                int krow = mt * 16 + l4 * 4 + r;
                qO[((size_t)b * SEQ + krow) * (NH * 64) + h * 64 + nt * 16 + l15] = O[mt][nt][r];
            }
}

extern "C" void kernel_launch(void* const* d_in, const int* in_sizes, int n_in,
                              void* d_out, int out_size, void* d_ws, size_t ws_size,
                              hipStream_t stream) {
    const float* query   = (const float*)d_in[0];
    const float* context = (const float*)d_in[1];
    const float* Wq      = (const float*)d_in[2];
    const float* bq      = (const float*)d_in[3];
    const float* Wc      = (const float*)d_in[4];
    const float* bc      = (const float*)d_in[5];
    float* out = (float*)d_out;

    unsigned short* wfrag = (unsigned short*)d_ws;            // 1 MB
    unsigned short* pp    = wfrag + 524288;                   // 134.2 MB
    const size_t need = (524288 + (size_t)2 * NB * NH * 4096) * sizeof(unsigned short);

    // bf16 activations live in d_out's storage (first 134 MB of 268 MB):
    // written by prep_acts, read by proj_direct, then fully overwritten by
    // tail_kernel. Stream-ordered; no cross-call state.
    unsigned short* acts = (unsigned short*)d_out;

    prep_weights<<<256, 256, 0, stream>>>(Wq, Wc, wfrag);
    if (ws_size >= need) {
        prep_acts<<<32768, 256, 0, stream>>>(query, context, acts);
        proj_direct<<<4096, 256, 0, stream>>>(acts, bq, bc, wfrag, pp);
        tail_kernel<<<2048, 256, 0, stream>>>(pp, out);
    } else {
        coattn_fused<<<NB * 2, 256, 0, stream>>>(query, context, bq, bc, wfrag, out);
    }
}

// Round 11
// 341.705 us; speedup vs baseline: 1.2261x; 1.2261x over previous
//
#include <hip/hip_runtime.h>
#include <hip/hip_bf16.h>

typedef float  f32x4 __attribute__((ext_vector_type(4)));
typedef short  s16x8 __attribute__((ext_vector_type(8)));

#define NB   1024
#define SEQ  64
#define DIM  512
#define NH   8
#define SCALE 0.044194173824159216f

// round-half-up f32->bf16: 2 VALU ops
static __device__ __forceinline__ unsigned short f2bf(float f) {
    unsigned u = __builtin_bit_cast(unsigned, f);
    return (unsigned short)((u + 0x8000u) >> 16);
}

static __device__ __forceinline__ f32x4 mma(s16x8 a, s16x8 b, f32x4 c) {
    return __builtin_amdgcn_mfma_f32_16x16x32_bf16(a, b, c, 0, 0, 0);
}

// load 8 consecutive f32, convert to a bf16 frag slice (fallback path)
static __device__ __forceinline__ s16x8 ldcvt(const float* p) {
    float4 v0 = *(const float4*)(p);
    float4 v1 = *(const float4*)(p + 4);
    s16x8 r;
    r[0] = (short)f2bf(v0.x); r[1] = (short)f2bf(v0.y);
    r[2] = (short)f2bf(v0.z); r[3] = (short)f2bf(v0.w);
    r[4] = (short)f2bf(v1.x); r[5] = (short)f2bf(v1.y);
    r[6] = (short)f2bf(v1.z); r[7] = (short)f2bf(v1.w);
    return r;
}

static __device__ __forceinline__ s16x8 cvt2(float4 a, float4 b) {
    s16x8 x;
    x[0] = (short)f2bf(a.x); x[1] = (short)f2bf(a.y);
    x[2] = (short)f2bf(a.z); x[3] = (short)f2bf(a.w);
    x[4] = (short)f2bf(b.x); x[5] = (short)f2bf(b.y);
    x[6] = (short)f2bf(b.z); x[7] = (short)f2bf(b.w);
    return x;
}

// Pre-kernel: Wq, Wc (f32 [512][512] row-major [k][n]) -> bf16 B-fragment order.
__global__ __launch_bounds__(256) void prep_weights(
    const float* __restrict__ Wq, const float* __restrict__ Wc,
    unsigned short* __restrict__ wf)
{
    int gid  = blockIdx.x * 256 + threadIdx.x;   // 0..65535
    int m    = gid >> 15;
    int tile = (gid >> 10) & 31;
    int ks   = (gid >> 6) & 15;
    int lane = gid & 63;
    const float* W = m ? Wc : Wq;
    int col = tile * 16 + (lane & 15);
    int k0  = ks * 32 + (lane >> 4) * 8;
    unsigned short* dst = wf + (size_t)gid * 8;
#pragma unroll
    for (int j = 0; j < 8; ++j)
        dst[j] = f2bf(W[(size_t)(k0 + j) * DIM + col]);
}

// ====================== Kernel 1: projections ======================
// One 256-thread block = one (b, m, 2-head group hg2); 4 waves =
// 2 heads x 2 row-halves, each wave a 32x64 output tile (acc = 32 AGPR).
// Small acc -> <=128 unified regs -> 4 waves/SIMD -> FOUR independent
// blocks/CU co-resident (R8's 512-thr/64-AGPR variant fit only ONE
// barrier-locked block/CU; that was the 2-phase stall). 16 KB LDS dbuf,
// R8's async-split staging, conflict-free [kk][q][row] slot layout.
// NOTE: plain __launch_bounds__ — a min-waves 2nd arg clamps the unified
// VGPR/AGPR budget below the accumulator and forces scratch spills
// (proved rounds 2 and 7: WRITE_SIZE +100 MB both times).
__global__ __launch_bounds__(256) void proj_kernel(
    const float* __restrict__ query,
    const float* __restrict__ context,
    const float* __restrict__ bq,
    const float* __restrict__ bc,
    const unsigned short* __restrict__ wf,
    unsigned short* __restrict__ pp)
{
    __shared__ unsigned short sA[2][4096];   // 2 x 512 slots x 16B = 16 KB

    const int tid  = threadIdx.x;
    const int lane = tid & 63;
    const int wv   = tid >> 6;        // 0..3
    const int l15  = lane & 15;
    const int l4   = lane >> 4;

    // XCD swizzle (grid 8192, %8==0 bijective): orig-consecutive blocks share
    // an XCD; the 4 hg2-blocks of one (b,m) are orig-adjacent -> act tile
    // staged from L2 after the first fetch.
    const int i    = blockIdx.x;
    const int orig = (i & 7) * 1024 + (i >> 3);
    const int b    = orig >> 3;
    const int m    = (orig >> 2) & 1;
    const int hg2  = orig & 3;
    const int h    = hg2 * 2 + (wv >> 1);   // head of this wave
    const int rh   = (wv & 1) * 32;         // row-half offset

    const float* act  = (m ? context : query) + (size_t)b * SEQ * DIM;
    const float* bias = m ? bc : bq;
    const unsigned short* wfm = wf + (size_t)m * 262144;

    // staging map: thread covers row=tid>>2, within-chunk cols (tid&3)*16..+15
    const int srow = tid >> 2;
    const int c0   = (tid & 3) * 16;
    const int kk0  = c0 >> 5;              // 0,0,1,1
    const int q0   = (c0 >> 3) & 3;        // 0,2,0,2
    const int slot1 = kk0 * 256 + q0 * 64 + srow; // kk*256 + q*64 + row
    const float* srcbase = act + (size_t)srow * DIM + c0;

    const f32x4 fz = {0.f, 0.f, 0.f, 0.f};
    f32x4 acc[2][4];
#pragma unroll
    for (int x = 0; x < 2; ++x)
#pragma unroll
        for (int y = 0; y < 4; ++y) acc[x][y] = fz;

    float4 st[4];

    // prologue: stage chunk 0
#pragma unroll
    for (int v = 0; v < 4; ++v) st[v] = *(const float4*)(srcbase + v * 4);
    *(s16x8*)&sA[0][slot1 * 8]        = cvt2(st[0], st[1]);
    *(s16x8*)&sA[0][(slot1 + 64) * 8] = cvt2(st[2], st[3]);
    __syncthreads();

#pragma unroll 2
    for (int c = 0; c < 8; ++c) {
        // (a) issue next chunk's global loads early (latency hides under (b))
        if (c < 7) {
            const float* s = srcbase + (c + 1) * 64;
#pragma unroll
            for (int v = 0; v < 4; ++v) st[v] = *(const float4*)(s + v * 4);
        }
        // (b) compute current chunk: 2 K-steps, 8 MFMA each
#pragma unroll
        for (int kk = 0; kk < 2; ++kk) {
            const int ksg = c * 2 + kk;
            s16x8 af[2], bf[4];
#pragma unroll
            for (int mt = 0; mt < 2; ++mt)
                af[mt] = *(const s16x8*)&sA[c & 1][(kk * 256 + l4 * 64 + rh + mt * 16 + l15) * 8];
#pragma unroll
            for (int nt = 0; nt < 4; ++nt)
                bf[nt] = *(const s16x8*)(wfm +
                         ((size_t)((h * 4 + nt) * 16 + ksg) * 64 + lane) * 8);
#pragma unroll
            for (int mt = 0; mt < 2; ++mt)
#pragma unroll
                for (int nt = 0; nt < 4; ++nt)
                    acc[mt][nt] = mma(af[mt], bf[nt], acc[mt][nt]);
        }
        // (c) cvt + write staged chunk AFTER compute (vmcnt wait lands here)
        if (c < 7) {
            const int s = (c + 1) & 1;
            *(s16x8*)&sA[s][slot1 * 8]        = cvt2(st[0], st[1]);
            *(s16x8*)&sA[s][(slot1 + 64) * 8] = cvt2(st[2], st[3]);
        }
        __syncthreads();
    }

    unsigned short* dst = pp + (((size_t)m * NB + b) * NH + h) * 4096;
#pragma unroll
    for (int nt = 0; nt < 4; ++nt) {
        float bv = bias[h * 64 + nt * 16 + l15];
#pragma unroll
        for (int mt = 0; mt < 2; ++mt)
#pragma unroll
            for (int r = 0; r < 4; ++r)
                dst[(rh + mt * 16 + l4 * 4 + r) * 64 + nt * 16 + l15] =
                    f2bf(acc[mt][nt][r] + bv);
    }
}

// ====================== Kernel 2: attention tail ======================
// One wave -> one (b,h). cb/qa as direct global frag loads; Qp staged in
// per-wave LDS only for the qb transpose; P1/P2^T reuse the same tile.
__global__ __launch_bounds__(256) void tail_kernel(
    const unsigned short* __restrict__ pp,
    float* __restrict__ out)
{
    __shared__ unsigned short sT[4][SEQ][72];

    const int lane = threadIdx.x & 63;
    const int wv   = threadIdx.x >> 6;
    const int l15  = lane & 15;
    const int l4   = lane >> 4;

    const int i    = blockIdx.x;
    const int orig = (i & 7) * 256 + (i >> 3);
    const int b    = orig >> 1;
    const int half = orig & 1;
    const int h    = half * 4 + wv;

    const unsigned short* qp = pp + ((size_t)b * NH + h) * 4096;
    const unsigned short* cp = pp + (((size_t)NB + b) * NH + h) * 4096;

    const f32x4 fz = {0.f, 0.f, 0.f, 0.f};
    unsigned short (*T)[72] = sT[wv];

    s16x8 cb[4][2], qa[4][2];
#pragma unroll
    for (int nt = 0; nt < 4; ++nt)
#pragma unroll
        for (int ks = 0; ks < 2; ++ks)
            cb[nt][ks] = *(const s16x8*)(cp + (nt * 16 + l15) * 64 + ks * 32 + l4 * 8);
#pragma unroll
    for (int mt = 0; mt < 4; ++mt)
#pragma unroll
        for (int ks = 0; ks < 2; ++ks)
            qa[mt][ks] = *(const s16x8*)(qp + (mt * 16 + l15) * 64 + ks * 32 + l4 * 8);

#pragma unroll
    for (int j = 0; j < 8; ++j) {
        int row = j * 8 + (lane >> 3);
        int col = (lane & 7) * 8;
        *(s16x8*)&T[row][col] = *(const s16x8*)(qp + row * 64 + col);
    }

    s16x8 qb[4][2];
#pragma unroll
    for (int nt = 0; nt < 4; ++nt)
#pragma unroll
        for (int ks = 0; ks < 2; ++ks) {
            s16x8 v;
#pragma unroll
            for (int j = 0; j < 8; ++j)
                v[j] = (short)T[ks * 32 + l4 * 8 + j][nt * 16 + l15];
            qb[nt][ks] = v;
        }

    f32x4 Sc[4][4];
#pragma unroll
    for (int x = 0; x < 4; ++x)
#pragma unroll
        for (int y = 0; y < 4; ++y) Sc[x][y] = fz;
#pragma unroll
    for (int ks = 0; ks < 2; ++ks)
#pragma unroll
        for (int mt = 0; mt < 4; ++mt)
#pragma unroll
            for (int nt = 0; nt < 4; ++nt)
                Sc[mt][nt] = mma(qa[mt][ks], cb[nt][ks], Sc[mt][nt]);

    // softmax over keys (rows): P1 -> T
#pragma unroll
    for (int mt = 0; mt < 4; ++mt)
#pragma unroll
        for (int r = 0; r < 4; ++r) {
            float m = fmaxf(fmaxf(Sc[mt][0][r], Sc[mt][1][r]),
                            fmaxf(Sc[mt][2][r], Sc[mt][3][r]));
            m = fmaxf(m, __shfl_xor(m, 1));
            m = fmaxf(m, __shfl_xor(m, 2));
            m = fmaxf(m, __shfl_xor(m, 4));
            m = fmaxf(m, __shfl_xor(m, 8));
            float e[4], s = 0.f;
#pragma unroll
            for (int nt = 0; nt < 4; ++nt) { e[nt] = __expf(SCALE * (Sc[mt][nt][r] - m)); s += e[nt]; }
            s += __shfl_xor(s, 1);
            s += __shfl_xor(s, 2);
            s += __shfl_xor(s, 4);
            s += __shfl_xor(s, 8);
            float inv = 1.f / s;
            int row = mt * 16 + l4 * 4 + r;
#pragma unroll
            for (int nt = 0; nt < 4; ++nt)
                T[row][nt * 16 + l15] = f2bf(e[nt] * inv);
        }

    s16x8 pa[4][2];
#pragma unroll
    for (int mt = 0; mt < 4; ++mt)
#pragma unroll
        for (int ks = 0; ks < 2; ++ks)
            pa[mt][ks] = *(const s16x8*)&T[mt * 16 + l15][ks * 32 + l4 * 8];

    // softmax over queries (cols): P2^T -> T
#pragma unroll
    for (int nt = 0; nt < 4; ++nt) {
        float m = -1e30f;
#pragma unroll
        for (int mt = 0; mt < 4; ++mt)
#pragma unroll
            for (int r = 0; r < 4; ++r) m = fmaxf(m, Sc[mt][nt][r]);
        m = fmaxf(m, __shfl_xor(m, 16));
        m = fmaxf(m, __shfl_xor(m, 32));
        float ee[4][4], s = 0.f;
#pragma unroll
        for (int mt = 0; mt < 4; ++mt)
#pragma unroll
            for (int r = 0; r < 4; ++r) { ee[mt][r] = __expf(SCALE * (Sc[mt][nt][r] - m)); s += ee[mt][r]; }
        s += __shfl_xor(s, 16);
        s += __shfl_xor(s, 32);
        float inv = 1.f / s;
        int krow = nt * 16 + l15;
#pragma unroll
        for (int mt = 0; mt < 4; ++mt)
#pragma unroll
            for (int r = 0; r < 4; ++r)
                T[krow][mt * 16 + l4 * 4 + r] = f2bf(ee[mt][r] * inv);
    }

    // c_coattn = P1 @ Cp^T
    f32x4 O[4][4];
#pragma unroll
    for (int x = 0; x < 4; ++x)
#pragma unroll
        for (int y = 0; y < 4; ++y) O[x][y] = fz;
#pragma unroll
    for (int ks = 0; ks < 2; ++ks)
#pragma unroll
        for (int mt = 0; mt < 4; ++mt)
#pragma unroll
            for (int nt = 0; nt < 4; ++nt)
                O[mt][nt] = mma(pa[mt][ks], cb[nt][ks], O[mt][nt]);

    float* cO = out;
#pragma unroll
    for (int mt = 0; mt < 4; ++mt)
#pragma unroll
        for (int nt = 0; nt < 4; ++nt)
#pragma unroll
            for (int r = 0; r < 4; ++r) {
                int qrow = mt * 16 + l4 * 4 + r;
                cO[((size_t)b * SEQ + qrow) * (NH * 64) + h * 64 + nt * 16 + l15] = O[mt][nt][r];
            }

    // q_coattn = P2^T @ Qp
    s16x8 p2a[4][2];
#pragma unroll
    for (int mt = 0; mt < 4; ++mt)
#pragma unroll
        for (int ks = 0; ks < 2; ++ks)
            p2a[mt][ks] = *(const s16x8*)&T[mt * 16 + l15][ks * 32 + l4 * 8];

#pragma unroll
    for (int x = 0; x < 4; ++x)
#pragma unroll
        for (int y = 0; y < 4; ++y) O[x][y] = fz;
#pragma unroll
    for (int ks = 0; ks < 2; ++ks)
#pragma unroll
        for (int mt = 0; mt < 4; ++mt)
#pragma unroll
            for (int nt = 0; nt < 4; ++nt)
                O[mt][nt] = mma(p2a[mt][ks], qb[nt][ks], O[mt][nt]);

    float* qO = out + (size_t)NB * SEQ * NH * 64;
#pragma unroll
    for (int mt = 0; mt < 4; ++mt)
#pragma unroll
        for (int nt = 0; nt < 4; ++nt)
#pragma unroll
            for (int r = 0; r < 4; ++r) {
                int krow = mt * 16 + l4 * 4 + r;
                qO[((size_t)b * SEQ + krow) * (NH * 64) + h * 64 + nt * 16 + l15] = O[mt][nt][r];
            }
}

// ====================== Fallback: fused (round-3 style) ======================
__global__ __launch_bounds__(256) void coattn_fused(
    const float* __restrict__ query,
    const float* __restrict__ context,
    const float* __restrict__ bq,
    const float* __restrict__ bc,
    const unsigned short* __restrict__ wf,
    float* __restrict__ out)
{
    __shared__ unsigned short sT[4][SEQ][72];
    const int tid  = threadIdx.x;
    const int lane = tid & 63;
    const int wv   = tid >> 6;
    const int l15  = lane & 15;
    const int l4   = lane >> 4;
    const int B_id = blockIdx.x;
    const int half = (B_id >> 3) & 1;
    const int b    = (B_id & 7) | ((B_id >> 4) << 3);
    const int h    = half * 4 + wv;
    const float* gq = query   + (size_t)b * SEQ * DIM;
    const float* gc = context + (size_t)b * SEQ * DIM;
    const f32x4 fz = {0.f, 0.f, 0.f, 0.f};
    unsigned short (*T)[72] = sT[wv];
    f32x4 acc[4][4];
#pragma unroll
    for (int i = 0; i < 4; ++i)
#pragma unroll
        for (int j = 0; j < 4; ++j) acc[i][j] = fz;
    for (int ks = 0; ks < 16; ++ks) {
        const int k0 = ks * 32 + l4 * 8;
        s16x8 af[4], bf[4];
#pragma unroll
        for (int mt = 0; mt < 4; ++mt)
            af[mt] = ldcvt(gc + (size_t)(mt * 16 + l15) * DIM + k0);
#pragma unroll
        for (int nt = 0; nt < 4; ++nt)
            bf[nt] = *(const s16x8*)(wf + 262144 +
                     ((size_t)((h * 4 + nt) * 16 + ks) * 64 + lane) * 8);
#pragma unroll
        for (int mt = 0; mt < 4; ++mt)
#pragma unroll
            for (int nt = 0; nt < 4; ++nt)
                acc[mt][nt] = mma(af[mt], bf[nt], acc[mt][nt]);
    }
#pragma unroll
    for (int nt = 0; nt < 4; ++nt) {
        float bcv = bc[h * 64 + nt * 16 + l15];
#pragma unroll
        for (int mt = 0; mt < 4; ++mt)
#pragma unroll
            for (int r = 0; r < 4; ++r)
                T[mt * 16 + l4 * 4 + r][nt * 16 + l15] = f2bf(acc[mt][nt][r] + bcv);
    }
    s16x8 cb[4][2];
#pragma unroll
    for (int nt = 0; nt < 4; ++nt)
#pragma unroll
        for (int ks = 0; ks < 2; ++ks)
            cb[nt][ks] = *(const s16x8*)&T[nt * 16 + l15][ks * 32 + l4 * 8];
#pragma unroll
    for (int i = 0; i < 4; ++i)
#pragma unroll
        for (int j = 0; j < 4; ++j) acc[i][j] = fz;
    for (int ks = 0; ks < 16; ++ks) {
        const int k0 = ks * 32 + l4 * 8;
        s16x8 af[4], bf[4];
#pragma unroll
        for (int mt = 0; mt < 4; ++mt)
            af[mt] = ldcvt(gq + (size_t)(mt * 16 + l15) * DIM + k0);
#pragma unroll
        for (int nt = 0; nt < 4; ++nt)
            bf[nt] = *(const s16x8*)(wf +
                     ((size_t)((h * 4 + nt) * 16 + ks) * 64 + lane) * 8);
#pragma unroll
        for (int mt = 0; mt < 4; ++mt)
#pragma unroll
            for (int nt = 0; nt < 4; ++nt)
                acc[mt][nt] = mma(af[mt], bf[nt], acc[mt][nt]);
    }
#pragma unroll
    for (int nt = 0; nt < 4; ++nt) {
        float bqv = bq[h * 64 + nt * 16 + l15];
#pragma unroll
        for (int mt = 0; mt < 4; ++mt)
#pragma unroll
            for (int r = 0; r < 4; ++r)
                T[mt * 16 + l4 * 4 + r][nt * 16 + l15] = f2bf(acc[mt][nt][r] + bqv);
    }
    s16x8 qa[4][2], qb[4][2];
#pragma unroll
    for (int mt = 0; mt < 4; ++mt)
#pragma unroll
        for (int ks = 0; ks < 2; ++ks)
            qa[mt][ks] = *(const s16x8*)&T[mt * 16 + l15][ks * 32 + l4 * 8];
#pragma unroll
    for (int nt = 0; nt < 4; ++nt)
#pragma unroll
        for (int ks = 0; ks < 2; ++ks) {
            s16x8 v;
#pragma unroll
            for (int j = 0; j < 8; ++j)
                v[j] = (short)T[ks * 32 + l4 * 8 + j][nt * 16 + l15];
            qb[nt][ks] = v;
        }
    f32x4 Sc[4][4];
#pragma unroll
    for (int i = 0; i < 4; ++i)
#pragma unroll
        for (int j = 0; j < 4; ++j) Sc[i][j] = fz;
#pragma unroll
    for (int ks = 0; ks < 2; ++ks)
#pragma unroll
        for (int mt = 0; mt < 4; ++mt)
#pragma unroll
            for (int nt = 0; nt < 4; ++nt)
                Sc[mt][nt] = mma(qa[mt][ks], cb[nt][ks], Sc[mt][nt]);
#pragma unroll
    for (int mt = 0; mt < 4; ++mt)
#pragma unroll
        for (int r = 0; r < 4; ++r) {
            float m = fmaxf(fmaxf(Sc[mt][0][r], Sc[mt][1][r]),
                            fmaxf(Sc[mt][2][r], Sc[mt][3][r]));
            m = fmaxf(m, __shfl_xor(m, 1));
            m = fmaxf(m, __shfl_xor(m, 2));
            m = fmaxf(m, __shfl_xor(m, 4));
            m = fmaxf(m, __shfl_xor(m, 8));
            float e[4], s = 0.f;
#pragma unroll
            for (int nt = 0; nt < 4; ++nt) { e[nt] = __expf(SCALE * (Sc[mt][nt][r] - m)); s += e[nt]; }
            s += __shfl_xor(s, 1);
            s += __shfl_xor(s, 2);
            s += __shfl_xor(s, 4);
            s += __shfl_xor(s, 8);
            float inv = 1.f / s;
            int row = mt * 16 + l4 * 4 + r;
#pragma unroll
            for (int nt = 0; nt < 4; ++nt)
                T[row][nt * 16 + l15] = f2bf(e[nt] * inv);
        }
    s16x8 pa[4][2];
#pragma unroll
    for (int mt = 0; mt < 4; ++mt)
#pragma unroll
        for (int ks = 0; ks < 2; ++ks)
            pa[mt][ks] = *(const s16x8*)&T[mt * 16 + l15][ks * 32 + l4 * 8];
#pragma unroll
    for (int nt = 0; nt < 4; ++nt) {
        float m = -1e30f;
#pragma unroll
        for (int mt = 0; mt < 4; ++mt)
#pragma unroll
            for (int r = 0; r < 4; ++r) m = fmaxf(m, Sc[mt][nt][r]);
        m = fmaxf(m, __shfl_xor(m, 16));
        m = fmaxf(m, __shfl_xor(m, 32));
        float ee[4][4], s = 0.f;
#pragma unroll
        for (int mt = 0; mt < 4; ++mt)
#pragma unroll
            for (int r = 0; r < 4; ++r) { ee[mt][r] = __expf(SCALE * (Sc[mt][nt][r] - m)); s += ee[mt][r]; }
        s += __shfl_xor(s, 16);
        s += __shfl_xor(s, 32);
        float inv = 1.f / s;
        int krow = nt * 16 + l15;
#pragma unroll
        for (int mt = 0; mt < 4; ++mt)
#pragma unroll
            for (int r = 0; r < 4; ++r)
                T[krow][mt * 16 + l4 * 4 + r] = f2bf(ee[mt][r] * inv);
    }
    s16x8 p2a[4][2];
#pragma unroll
    for (int mt = 0; mt < 4; ++mt)
#pragma unroll
        for (int ks = 0; ks < 2; ++ks)
            p2a[mt][ks] = *(const s16x8*)&T[mt * 16 + l15][ks * 32 + l4 * 8];
    f32x4 O[4][4];
#pragma unroll
    for (int i = 0; i < 4; ++i)
#pragma unroll
        for (int j = 0; j < 4; ++j) O[i][j] = fz;
#pragma unroll
    for (int ks = 0; ks < 2; ++ks)
#pragma unroll
        for (int mt = 0; mt < 4; ++mt)
#pragma unroll
            for (int nt = 0; nt < 4; ++nt)
                O[mt][nt] = mma(pa[mt][ks], cb[nt][ks], O[mt][nt]);
    float* cO = out;
#pragma unroll
    for (int mt = 0; mt < 4; ++mt)
#pragma unroll
        for (int nt = 0; nt < 4; ++nt)
#pragma unroll
            for (int r = 0; r < 4; ++r) {
                int qrow = mt * 16 + l4 * 4 + r;
                cO[((size_t)b * SEQ + qrow) * (NH * 64) + h * 64 + nt * 16 + l15] = O[mt][nt][r];
            }
#pragma unroll
    for (int i = 0; i < 4; ++i)
#pragma unroll
        for (int j = 0; j < 4; ++j) O[i][j] = fz;
#pragma unroll
    for (int ks = 0; ks < 2; ++ks)
#pragma unroll
        for (int mt = 0; mt < 4; ++mt)
#pragma unroll
            for (int nt = 0; nt < 4; ++nt)
                O[mt][nt] = mma(p2a[mt][ks], qb[nt][ks], O[mt][nt]);
    float* qO = out + (size_t)NB * SEQ * NH * 64;
#pragma unroll
    for (int mt = 0; mt < 4; ++mt)
#pragma unroll
        for (int nt = 0; nt < 4; ++nt)
#pragma unroll
            for (int r = 0; r < 4; ++r) {
                int krow = mt * 16 + l4 * 4 + r;
                qO[((size_t)b * SEQ + krow) * (NH * 64) + h * 64 + nt * 16 + l15] = O[mt][nt][r];
            }
}

extern "C" void kernel_launch(void* const* d_in, const int* in_sizes, int n_in,
                              void* d_out, int out_size, void* d_ws, size_t ws_size,
                              hipStream_t stream) {
    const float* query   = (const float*)d_in[0];
    const float* context = (const float*)d_in[1];
    const float* Wq      = (const float*)d_in[2];
    const float* bq      = (const float*)d_in[3];
    const float* Wc      = (const float*)d_in[4];
    const float* bc      = (const float*)d_in[5];
    float* out = (float*)d_out;

    unsigned short* wfrag = (unsigned short*)d_ws;            // 1 MB
    unsigned short* pp    = wfrag + 524288;                   // 134.2 MB
    const size_t need = (524288 + (size_t)2 * NB * NH * 4096) * sizeof(unsigned short);

    prep_weights<<<256, 256, 0, stream>>>(Wq, Wc, wfrag);
    if (ws_size >= need) {
        proj_kernel<<<8192, 256, 0, stream>>>(query, context, bq, bc, wfrag, pp);
        tail_kernel<<<2048, 256, 0, stream>>>(pp, out);
    } else {
        coattn_fused<<<NB * 2, 256, 0, stream>>>(query, context, bq, bc, wfrag, out);
    }
}

// Round 12
// 266.602 us; speedup vs baseline: 1.5714x; 1.2817x over previous
//
#include <hip/hip_runtime.h>
#include <hip/hip_bf16.h>

typedef float  f32x4 __attribute__((ext_vector_type(4)));
typedef short  s16x8 __attribute__((ext_vector_type(8)));

#define NB   1024
#define SEQ  64
#define DIM  512
#define NH   8
#define SCALE 0.044194173824159216f

// round-half-up f32->bf16: 2 VALU ops
static __device__ __forceinline__ unsigned short f2bf(float f) {
    unsigned u = __builtin_bit_cast(unsigned, f);
    return (unsigned short)((u + 0x8000u) >> 16);
}

static __device__ __forceinline__ f32x4 mma(s16x8 a, s16x8 b, f32x4 c) {
    return __builtin_amdgcn_mfma_f32_16x16x32_bf16(a, b, c, 0, 0, 0);
}

// load 8 consecutive f32, convert to a bf16 frag slice (fallback path)
static __device__ __forceinline__ s16x8 ldcvt(const float* p) {
    float4 v0 = *(const float4*)(p);
    float4 v1 = *(const float4*)(p + 4);
    s16x8 r;
    r[0] = (short)f2bf(v0.x); r[1] = (short)f2bf(v0.y);
    r[2] = (short)f2bf(v0.z); r[3] = (short)f2bf(v0.w);
    r[4] = (short)f2bf(v1.x); r[5] = (short)f2bf(v1.y);
    r[6] = (short)f2bf(v1.z); r[7] = (short)f2bf(v1.w);
    return r;
}

static __device__ __forceinline__ s16x8 cvt2(float4 a, float4 b) {
    s16x8 x;
    x[0] = (short)f2bf(a.x); x[1] = (short)f2bf(a.y);
    x[2] = (short)f2bf(a.z); x[3] = (short)f2bf(a.w);
    x[4] = (short)f2bf(b.x); x[5] = (short)f2bf(b.y);
    x[6] = (short)f2bf(b.z); x[7] = (short)f2bf(b.w);
    return x;
}

// Pre-kernel: Wq, Wc (f32 [512][512] row-major [k][n]) -> bf16 B-fragment order.
__global__ __launch_bounds__(256) void prep_weights(
    const float* __restrict__ Wq, const float* __restrict__ Wc,
    unsigned short* __restrict__ wf)
{
    int gid  = blockIdx.x * 256 + threadIdx.x;   // 0..65535
    int m    = gid >> 15;
    int tile = (gid >> 10) & 31;
    int ks   = (gid >> 6) & 15;
    int lane = gid & 63;
    const float* W = m ? Wc : Wq;
    int col = tile * 16 + (lane & 15);
    int k0  = ks * 32 + (lane >> 4) * 8;
    unsigned short* dst = wf + (size_t)gid * 8;
#pragma unroll
    for (int j = 0; j < 8; ++j)
        dst[j] = f2bf(W[(size_t)(k0 + j) * DIM + col]);
}

// ====================== Kernel 1: persistent projections ======================
// Grid 256 x 512 threads: one block per CU, each owns 8 (b,m) tiles =
// 16 half-tiles (64 rows x 256 cols). Cross-tile double-buffer (2 x 32 KB):
// per half-step {issue next-half loads -> compute 8 K-steps from cur buf ->
// cvt+ds_write next half -> barrier}. Only the FIRST stage per block is
// exposed; all other HBM latency hides under a full compute phase.
//
// LDS layout per half-buffer: slot s = p*512 + kk*256 + q*64 + row
// (p = 64-col pass, kk/q = col subdivisions), stored at s ^ key where
// key = (col>>3)&7. Write key = cw (=tid&7), read key = 4*kk+l4 —
// spreads each 8-lane phase group across all 8 bank-start residues:
// conflict-free ds_write_b128 AND ds_read_b128 (R6/R11's 5-12M conflicts
// came from unswizzled maps with 4-8 lanes/row).
// NOTE: plain __launch_bounds__ — a min-waves 2nd arg clamps the unified
// VGPR/AGPR budget below the 64-AGPR accumulator -> scratch spills
// (proved rounds 2 and 7).
__global__ __launch_bounds__(512) void proj_persist(
    const float* __restrict__ query,
    const float* __restrict__ context,
    const float* __restrict__ bq,
    const float* __restrict__ bc,
    const unsigned short* __restrict__ wf,
    unsigned short* __restrict__ pp)
{
    __shared__ unsigned short sB[2][16384];   // 2 x 32 KB (2048 slots x 16B)

    const int tid  = threadIdx.x;
    const int lane = tid & 63;
    const int wv   = tid >> 6;         // wave id = head
    const int l15  = lane & 15;
    const int l4   = lane >> 4;
    const int row  = tid >> 3;         // staging row 0..63
    const int cw   = tid & 7;          // staging col-chunk (8 f32)
    const int wslotbase = (cw >> 2) * 256 + (cw & 3) * 64 + row;

    const int tbase = blockIdx.x * 8;  // 8 (b,m) tiles per block

    const f32x4 fz = {0.f, 0.f, 0.f, 0.f};
    f32x4 acc[4][4];
#pragma unroll
    for (int x = 0; x < 4; ++x)
#pragma unroll
        for (int y = 0; y < 4; ++y) acc[x][y] = fz;

    // prologue: stage half 0 of tile tbase into buf 0 (the only exposed stage)
    {
        const int T = tbase;
        const float* act = ((T & 1) ? context : query) + (size_t)(T >> 1) * SEQ * DIM;
        const float* srcp = act + (size_t)row * DIM + cw * 8;
#pragma unroll
        for (int p = 0; p < 4; ++p) {
            float4 a = *(const float4*)(srcp + p * 64);
            float4 b = *(const float4*)(srcp + p * 64 + 4);
            *(s16x8*)&sB[0][((p * 512 + wslotbase) ^ cw) * 8] = cvt2(a, b);
        }
    }
    __syncthreads();

#pragma unroll 2
    for (int h = 0; h < 16; ++h) {
        const unsigned short* cur = sB[h & 1];
        unsigned short* nxt = sB[(h + 1) & 1];
        const int T    = tbase + (h >> 1);
        const int half = h & 1;

        // (a) issue next half's global loads early (consumed in (c))
        float4 st[8];
        if (h < 15) {
            const int Tn = tbase + ((h + 1) >> 1);
            const float* actn = ((Tn & 1) ? context : query)
                                + (size_t)(Tn >> 1) * SEQ * DIM;
            const float* srcp = actn + (size_t)row * DIM
                                + ((h + 1) & 1) * 256 + cw * 8;
#pragma unroll
            for (int p = 0; p < 4; ++p) {
                st[2 * p]     = *(const float4*)(srcp + p * 64);
                st[2 * p + 1] = *(const float4*)(srcp + p * 64 + 4);
            }
        }

        // (b) compute 8 K-steps of this half from cur
        const unsigned short* wfm = wf + (size_t)(T & 1) * 262144;
#pragma unroll
        for (int ksg = 0; ksg < 8; ++ksg) {
            const int ks = half * 8 + ksg;
            const int p  = ksg >> 1;
            const int kk = ksg & 1;
            s16x8 af[4], bf[4];
#pragma unroll
            for (int mt = 0; mt < 4; ++mt) {
                const int s = p * 512 + kk * 256 + l4 * 64 + mt * 16 + l15;
                af[mt] = *(const s16x8*)&cur[(s ^ (4 * kk + l4)) * 8];
            }
#pragma unroll
            for (int nt = 0; nt < 4; ++nt)
                bf[nt] = *(const s16x8*)(wfm +
                         ((size_t)((wv * 4 + nt) * 16 + ks) * 64 + lane) * 8);
#pragma unroll
            for (int mt = 0; mt < 4; ++mt)
#pragma unroll
                for (int nt = 0; nt < 4; ++nt)
                    acc[mt][nt] = mma(af[mt], bf[nt], acc[mt][nt]);
        }

        // (c) cvt + write the staged half (vmcnt wait lands here, hidden)
        if (h < 15) {
#pragma unroll
            for (int p = 0; p < 4; ++p)
                *(s16x8*)&nxt[((p * 512 + wslotbase) ^ cw) * 8] =
                    cvt2(st[2 * p], st[2 * p + 1]);
        }

        // (d) per-tile epilogue: bias + store Cp/Qp, reset acc
        if (half == 1) {
            const int b = T >> 1, m = T & 1;
            const float* bias = m ? bc : bq;
            unsigned short* dst = pp + (((size_t)m * NB + b) * NH + wv) * 4096;
#pragma unroll
            for (int nt = 0; nt < 4; ++nt) {
                float bv = bias[wv * 64 + nt * 16 + l15];
#pragma unroll
                for (int mt = 0; mt < 4; ++mt)
#pragma unroll
                    for (int r = 0; r < 4; ++r)
                        dst[(mt * 16 + l4 * 4 + r) * 64 + nt * 16 + l15] =
                            f2bf(acc[mt][nt][r] + bv);
            }
#pragma unroll
            for (int x = 0; x < 4; ++x)
#pragma unroll
                for (int y = 0; y < 4; ++y) acc[x][y] = fz;
        }
        __syncthreads();
    }
}

// ====================== Kernel 2: attention tail ======================
// One wave -> one (b,h). cb/qa as direct global frag loads; Qp staged in
// per-wave LDS only for the qb transpose; P1/P2^T reuse the same tile.
__global__ __launch_bounds__(256) void tail_kernel(
    const unsigned short* __restrict__ pp,
    float* __restrict__ out)
{
    __shared__ unsigned short sT[4][SEQ][72];

    const int lane = threadIdx.x & 63;
    const int wv   = threadIdx.x >> 6;
    const int l15  = lane & 15;
    const int l4   = lane >> 4;

    const int i    = blockIdx.x;
    const int orig = (i & 7) * 256 + (i >> 3);
    const int b    = orig >> 1;
    const int half = orig & 1;
    const int h    = half * 4 + wv;

    const unsigned short* qp = pp + ((size_t)b * NH + h) * 4096;
    const unsigned short* cp = pp + (((size_t)NB + b) * NH + h) * 4096;

    const f32x4 fz = {0.f, 0.f, 0.f, 0.f};
    unsigned short (*T)[72] = sT[wv];

    s16x8 cb[4][2], qa[4][2];
#pragma unroll
    for (int nt = 0; nt < 4; ++nt)
#pragma unroll
        for (int ks = 0; ks < 2; ++ks)
            cb[nt][ks] = *(const s16x8*)(cp + (nt * 16 + l15) * 64 + ks * 32 + l4 * 8);
#pragma unroll
    for (int mt = 0; mt < 4; ++mt)
#pragma unroll
        for (int ks = 0; ks < 2; ++ks)
            qa[mt][ks] = *(const s16x8*)(qp + (mt * 16 + l15) * 64 + ks * 32 + l4 * 8);

#pragma unroll
    for (int j = 0; j < 8; ++j) {
        int r2 = j * 8 + (lane >> 3);
        int c2 = (lane & 7) * 8;
        *(s16x8*)&T[r2][c2] = *(const s16x8*)(qp + r2 * 64 + c2);
    }

    s16x8 qb[4][2];
#pragma unroll
    for (int nt = 0; nt < 4; ++nt)
#pragma unroll
        for (int ks = 0; ks < 2; ++ks) {
            s16x8 v;
#pragma unroll
            for (int j = 0; j < 8; ++j)
                v[j] = (short)T[ks * 32 + l4 * 8 + j][nt * 16 + l15];
            qb[nt][ks] = v;
        }

    f32x4 Sc[4][4];
#pragma unroll
    for (int x = 0; x < 4; ++x)
#pragma unroll
        for (int y = 0; y < 4; ++y) Sc[x][y] = fz;
#pragma unroll
    for (int ks = 0; ks < 2; ++ks)
#pragma unroll
        for (int mt = 0; mt < 4; ++mt)
#pragma unroll
            for (int nt = 0; nt < 4; ++nt)
                Sc[mt][nt] = mma(qa[mt][ks], cb[nt][ks], Sc[mt][nt]);

    // softmax over keys (rows): P1 -> T
#pragma unroll
    for (int mt = 0; mt < 4; ++mt)
#pragma unroll
        for (int r = 0; r < 4; ++r) {
            float m = fmaxf(fmaxf(Sc[mt][0][r], Sc[mt][1][r]),
                            fmaxf(Sc[mt][2][r], Sc[mt][3][r]));
            m = fmaxf(m, __shfl_xor(m, 1));
            m = fmaxf(m, __shfl_xor(m, 2));
            m = fmaxf(m, __shfl_xor(m, 4));
            m = fmaxf(m, __shfl_xor(m, 8));
            float e[4], s = 0.f;
#pragma unroll
            for (int nt = 0; nt < 4; ++nt) { e[nt] = __expf(SCALE * (Sc[mt][nt][r] - m)); s += e[nt]; }
            s += __shfl_xor(s, 1);
            s += __shfl_xor(s, 2);
            s += __shfl_xor(s, 4);
            s += __shfl_xor(s, 8);
            float inv = 1.f / s;
            int r3 = mt * 16 + l4 * 4 + r;
#pragma unroll
            for (int nt = 0; nt < 4; ++nt)
                T[r3][nt * 16 + l15] = f2bf(e[nt] * inv);
        }

    s16x8 pa[4][2];
#pragma unroll
    for (int mt = 0; mt < 4; ++mt)
#pragma unroll
        for (int ks = 0; ks < 2; ++ks)
            pa[mt][ks] = *(const s16x8*)&T[mt * 16 + l15][ks * 32 + l4 * 8];

    // softmax over queries (cols): P2^T -> T
#pragma unroll
    for (int nt = 0; nt < 4; ++nt) {
        float m = -1e30f;
#pragma unroll
        for (int mt = 0; mt < 4; ++mt)
#pragma unroll
            for (int r = 0; r < 4; ++r) m = fmaxf(m, Sc[mt][nt][r]);
        m = fmaxf(m, __shfl_xor(m, 16));
        m = fmaxf(m, __shfl_xor(m, 32));
        float ee[4][4], s = 0.f;
#pragma unroll
        for (int mt = 0; mt < 4; ++mt)
#pragma unroll
            for (int r = 0; r < 4; ++r) { ee[mt][r] = __expf(SCALE * (Sc[mt][nt][r] - m)); s += ee[mt][r]; }
        s += __shfl_xor(s, 16);
        s += __shfl_xor(s, 32);
        float inv = 1.f / s;
        int krow = nt * 16 + l15;
#pragma unroll
        for (int mt = 0; mt < 4; ++mt)
#pragma unroll
            for (int r = 0; r < 4; ++r)
                T[krow][mt * 16 + l4 * 4 + r] = f2bf(ee[mt][r] * inv);
    }

    // c_coattn = P1 @ Cp^T
    f32x4 O[4][4];
#pragma unroll
    for (int x = 0; x < 4; ++x)
#pragma unroll
        for (int y = 0; y < 4; ++y) O[x][y] = fz;
#pragma unroll
    for (int ks = 0; ks < 2; ++ks)
#pragma unroll
        for (int mt = 0; mt < 4; ++mt)
#pragma unroll
            for (int nt = 0; nt < 4; ++nt)
                O[mt][nt] = mma(pa[mt][ks], cb[nt][ks], O[mt][nt]);

    float* cO = out;
#pragma unroll
    for (int mt = 0; mt < 4; ++mt)
#pragma unroll
        for (int nt = 0; nt < 4; ++nt)
#pragma unroll
            for (int r = 0; r < 4; ++r) {
                int qrow = mt * 16 + l4 * 4 + r;
                cO[((size_t)b * SEQ + qrow) * (NH * 64) + h * 64 + nt * 16 + l15] = O[mt][nt][r];
            }

    // q_coattn = P2^T @ Qp
    s16x8 p2a[4][2];
#pragma unroll
    for (int mt = 0; mt < 4; ++mt)
#pragma unroll
        for (int ks = 0; ks < 2; ++ks)
            p2a[mt][ks] = *(const s16x8*)&T[mt * 16 + l15][ks * 32 + l4 * 8];

#pragma unroll
    for (int x = 0; x < 4; ++x)
#pragma unroll
        for (int y = 0; y < 4; ++y) O[x][y] = fz;
#pragma unroll
    for (int ks = 0; ks < 2; ++ks)
#pragma unroll
        for (int mt = 0; mt < 4; ++mt)
#pragma unroll
            for (int nt = 0; nt < 4; ++nt)
                O[mt][nt] = mma(p2a[mt][ks], qb[nt][ks], O[mt][nt]);

    float* qO = out + (size_t)NB * SEQ * NH * 64;
#pragma unroll
    for (int mt = 0; mt < 4; ++mt)
#pragma unroll
        for (int nt = 0; nt < 4; ++nt)
#pragma unroll
            for (int r = 0; r < 4; ++r) {
                int krow = mt * 16 + l4 * 4 + r;
                qO[((size_t)b * SEQ + krow) * (NH * 64) + h * 64 + nt * 16 + l15] = O[mt][nt][r];
            }
}

// ====================== Fallback: fused (round-3 style) ======================
__global__ __launch_bounds__(256) void coattn_fused(
    const float* __restrict__ query,
    const float* __restrict__ context,
    const float* __restrict__ bq,
    const float* __restrict__ bc,
    const unsigned short* __restrict__ wf,
    float* __restrict__ out)
{
    __shared__ unsigned short sT[4][SEQ][72];
    const int tid  = threadIdx.x;
    const int lane = tid & 63;
    const int wv   = tid >> 6;
    const int l15  = lane & 15;
    const int l4   = lane >> 4;
    const int B_id = blockIdx.x;
    const int half = (B_id >> 3) & 1;
    const int b    = (B_id & 7) | ((B_id >> 4) << 3);
    const int h    = half * 4 + wv;
    const float* gq = query   + (size_t)b * SEQ * DIM;
    const float* gc = context + (size_t)b * SEQ * DIM;
    const f32x4 fz = {0.f, 0.f, 0.f, 0.f};
    unsigned short (*T)[72] = sT[wv];
    f32x4 acc[4][4];
#pragma unroll
    for (int i = 0; i < 4; ++i)
#pragma unroll
        for (int j = 0; j < 4; ++j) acc[i][j] = fz;
    for (int ks = 0; ks < 16; ++ks) {
        const int k0 = ks * 32 + l4 * 8;
        s16x8 af[4], bf[4];
#pragma unroll
        for (int mt = 0; mt < 4; ++mt)
            af[mt] = ldcvt(gc + (size_t)(mt * 16 + l15) * DIM + k0);
#pragma unroll
        for (int nt = 0; nt < 4; ++nt)
            bf[nt] = *(const s16x8*)(wf + 262144 +
                     ((size_t)((h * 4 + nt) * 16 + ks) * 64 + lane) * 8);
#pragma unroll
        for (int mt = 0; mt < 4; ++mt)
#pragma unroll
            for (int nt = 0; nt < 4; ++nt)
                acc[mt][nt] = mma(af[mt], bf[nt], acc[mt][nt]);
    }
#pragma unroll
    for (int nt = 0; nt < 4; ++nt) {
        float bcv = bc[h * 64 + nt * 16 + l15];
#pragma unroll
        for (int mt = 0; mt < 4; ++mt)
#pragma unroll
            for (int r = 0; r < 4; ++r)
                T[mt * 16 + l4 * 4 + r][nt * 16 + l15] = f2bf(acc[mt][nt][r] + bcv);
    }
    s16x8 cb[4][2];
#pragma unroll
    for (int nt = 0; nt < 4; ++nt)
#pragma unroll
        for (int ks = 0; ks < 2; ++ks)
            cb[nt][ks] = *(const s16x8*)&T[nt * 16 + l15][ks * 32 + l4 * 8];
#pragma unroll
    for (int i = 0; i < 4; ++i)
#pragma unroll
        for (int j = 0; j < 4; ++j) acc[i][j] = fz;
    for (int ks = 0; ks < 16; ++ks) {
        const int k0 = ks * 32 + l4 * 8;
        s16x8 af[4], bf[4];
#pragma unroll
        for (int mt = 0; mt < 4; ++mt)
            af[mt] = ldcvt(gq + (size_t)(mt * 16 + l15) * DIM + k0);
#pragma unroll
        for (int nt = 0; nt < 4; ++nt)
            bf[nt] = *(const s16x8*)(wf +
                     ((size_t)((h * 4 + nt) * 16 + ks) * 64 + lane) * 8);
#pragma unroll
        for (int mt = 0; mt < 4; ++mt)
#pragma unroll
            for (int nt = 0; nt < 4; ++nt)
                acc[mt][nt] = mma(af[mt], bf[nt], acc[mt][nt]);
    }
#pragma unroll
    for (int nt = 0; nt < 4; ++nt) {
        float bqv = bq[h * 64 + nt * 16 + l15];
#pragma unroll
        for (int mt = 0; mt < 4; ++mt)
#pragma unroll
            for (int r = 0; r < 4; ++r)
                T[mt * 16 + l4 * 4 + r][nt * 16 + l15] = f2bf(acc[mt][nt][r] + bqv);
    }
    s16x8 qa[4][2], qb[4][2];
#pragma unroll
    for (int mt = 0; mt < 4; ++mt)
#pragma unroll
        for (int ks = 0; ks < 2; ++ks)
            qa[mt][ks] = *(const s16x8*)&T[mt * 16 + l15][ks * 32 + l4 * 8];
#pragma unroll
    for (int nt = 0; nt < 4; ++nt)
#pragma unroll
        for (int ks = 0; ks < 2; ++ks) {
            s16x8 v;
#pragma unroll
            for (int j = 0; j < 8; ++j)
                v[j] = (short)T[ks * 32 + l4 * 8 + j][nt * 16 + l15];
            qb[nt][ks] = v;
        }
    f32x4 Sc[4][4];
#pragma unroll
    for (int i = 0; i < 4; ++i)
#pragma unroll
        for (int j = 0; j < 4; ++j) Sc[i][j] = fz;
#pragma unroll
    for (int ks = 0; ks < 2; ++ks)
#pragma unroll
        for (int mt = 0; mt < 4; ++mt)
#pragma unroll
            for (int nt = 0; nt < 4; ++nt)
                Sc[mt][nt] = mma(qa[mt][ks], cb[nt][ks], Sc[mt][nt]);
#pragma unroll
    for (int mt = 0; mt < 4; ++mt)
#pragma unroll
        for (int r = 0; r < 4; ++r) {
            float m = fmaxf(fmaxf(Sc[mt][0][r], Sc[mt][1][r]),
                            fmaxf(Sc[mt][2][r], Sc[mt][3][r]));
            m = fmaxf(m, __shfl_xor(m, 1));
            m = fmaxf(m, __shfl_xor(m, 2));
            m = fmaxf(m, __shfl_xor(m, 4));
            m = fmaxf(m, __shfl_xor(m, 8));
            float e[4], s = 0.f;
#pragma unroll
            for (int nt = 0; nt < 4; ++nt) { e[nt] = __expf(SCALE * (Sc[mt][nt][r] - m)); s += e[nt]; }
            s += __shfl_xor(s, 1);
            s += __shfl_xor(s, 2);
            s += __shfl_xor(s, 4);
            s += __shfl_xor(s, 8);
            float inv = 1.f / s;
            int row = mt * 16 + l4 * 4 + r;
#pragma unroll
            for (int nt = 0; nt < 4; ++nt)
                T[row][nt * 16 + l15] = f2bf(e[nt] * inv);
        }
    s16x8 pa[4][2];
#pragma unroll
    for (int mt = 0; mt < 4; ++mt)
#pragma unroll
        for (int ks = 0; ks < 2; ++ks)
            pa[mt][ks] = *(const s16x8*)&T[mt * 16 + l15][ks * 32 + l4 * 8];
#pragma unroll
    for (int nt = 0; nt < 4; ++nt) {
        float m = -1e30f;
#pragma unroll
        for (int mt = 0; mt < 4; ++mt)
#pragma unroll
            for (int r = 0; r < 4; ++r) m = fmaxf(m, Sc[mt][nt][r]);
        m = fmaxf(m, __shfl_xor(m, 16));
        m = fmaxf(m, __shfl_xor(m, 32));
        float ee[4][4], s = 0.f;
#pragma unroll
        for (int mt = 0; mt < 4; ++mt)
#pragma unroll
            for (int r = 0; r < 4; ++r) { ee[mt][r] = __expf(SCALE * (Sc[mt][nt][r] - m)); s += ee[mt][r]; }
        s += __shfl_xor(s, 16);
        s += __shfl_xor(s, 32);
        float inv = 1.f / s;
        int krow = nt * 16 + l15;
#pragma unroll
        for (int mt = 0; mt < 4; ++mt)
#pragma unroll
            for (int r = 0; r < 4; ++r)
                T[krow][mt * 16 + l4 * 4 + r] = f2bf(ee[mt][r] * inv);
    }
    s16x8 p2a[4][2];
#pragma unroll
    for (int mt = 0; mt < 4; ++mt)
#pragma unroll
        for (int ks = 0; ks < 2; ++ks)
            p2a[mt][ks] = *(const s16x8*)&T[mt * 16 + l15][ks * 32 + l4 * 8];
    f32x4 O[4][4];
#pragma unroll
    for (int i = 0; i < 4; ++i)
#pragma unroll
        for (int j = 0; j < 4; ++j) O[i][j] = fz;
#pragma unroll
    for (int ks = 0; ks < 2; ++ks)
#pragma unroll
        for (int mt = 0; mt < 4; ++mt)
#pragma unroll
            for (int nt = 0; nt < 4; ++nt)
                O[mt][nt] = mma(pa[mt][ks], cb[nt][ks], O[mt][nt]);
    float* cO = out;
#pragma unroll
    for (int mt = 0; mt < 4; ++mt)
#pragma unroll
        for (int nt = 0; nt < 4; ++nt)
#pragma unroll
            for (int r = 0; r < 4; ++r) {
                int qrow = mt * 16 + l4 * 4 + r;
                cO[((size_t)b * SEQ + qrow) * (NH * 64) + h * 64 + nt * 16 + l15] = O[mt][nt][r];
            }
#pragma unroll
    for (int i = 0; i < 4; ++i)
#pragma unroll
        for (int j = 0; j < 4; ++j) O[i][j] = fz;
#pragma unroll
    for (int ks = 0; ks < 2; ++ks)
#pragma unroll
        for (int mt = 0; mt < 4; ++mt)
#pragma unroll
            for (int nt = 0; nt < 4; ++nt)
                O[mt][nt] = mma(p2a[mt][ks], qb[nt][ks], O[mt][nt]);
    float* qO = out + (size_t)NB * SEQ * NH * 64;
#pragma unroll
    for (int mt = 0; mt < 4; ++mt)
#pragma unroll
        for (int nt = 0; nt < 4; ++nt)
#pragma unroll
            for (int r = 0; r < 4; ++r) {
                int krow = mt * 16 + l4 * 4 + r;
                qO[((size_t)b * SEQ + krow) * (NH * 64) + h * 64 + nt * 16 + l15] = O[mt][nt][r];
            }
}

extern "C" void kernel_launch(void* const* d_in, const int* in_sizes, int n_in,
                              void* d_out, int out_size, void* d_ws, size_t ws_size,
                              hipStream_t stream) {
    const float* query   = (const float*)d_in[0];
    const float* context = (const float*)d_in[1];
    const float* Wq      = (const float*)d_in[2];
    const float* bq      = (const float*)d_in[3];
    const float* Wc      = (const float*)d_in[4];
    const float* bc      = (const float*)d_in[5];
    float* out = (float*)d_out;

    unsigned short* wfrag = (unsigned short*)d_ws;            // 1 MB
    unsigned short* pp    = wfrag + 524288;                   // 134.2 MB
    const size_t need = (524288 + (size_t)2 * NB * NH * 4096) * sizeof(unsigned short);

    prep_weights<<<256, 256, 0, stream>>>(Wq, Wc, wfrag);
    if (ws_size >= need) {
        proj_persist<<<256, 512, 0, stream>>>(query, context, bq, bc, wfrag, pp);
        tail_kernel<<<2048, 256, 0, stream>>>(pp, out);
    } else {
        coattn_fused<<<NB * 2, 256, 0, stream>>>(query, context, bq, bc, wfrag, out);
    }
}

// Round 13
// 181.685 us; speedup vs baseline: 2.3059x; 1.4674x over previous
//
#include <hip/hip_runtime.h>
#include <hip/hip_bf16.h>

typedef float  f32x4 __attribute__((ext_vector_type(4)));
typedef short  s16x8 __attribute__((ext_vector_type(8)));

#define NB   1024
#define SEQ  64
#define DIM  512
#define NH   8
#define SCALE 0.044194173824159216f

// round-half-up f32->bf16: 2 VALU ops
static __device__ __forceinline__ unsigned short f2bf(float f) {
    unsigned u = __builtin_bit_cast(unsigned, f);
    return (unsigned short)((u + 0x8000u) >> 16);
}

static __device__ __forceinline__ f32x4 mma(s16x8 a, s16x8 b, f32x4 c) {
    return __builtin_amdgcn_mfma_f32_16x16x32_bf16(a, b, c, 0, 0, 0);
}

static __device__ __forceinline__ s16x8 cvt2(float4 a, float4 b) {
    s16x8 x;
    x[0] = (short)f2bf(a.x); x[1] = (short)f2bf(a.y);
    x[2] = (short)f2bf(a.z); x[3] = (short)f2bf(a.w);
    x[4] = (short)f2bf(b.x); x[5] = (short)f2bf(b.y);
    x[6] = (short)f2bf(b.z); x[7] = (short)f2bf(b.w);
    return x;
}

// Pre-kernel: Wq, Wc (f32 [512][512] row-major [k][n]) -> bf16 B-fragment order.
__global__ __launch_bounds__(256) void prep_weights(
    const float* __restrict__ Wq, const float* __restrict__ Wc,
    unsigned short* __restrict__ wf)
{
    int gid  = blockIdx.x * 256 + threadIdx.x;   // 0..65535
    int m    = gid >> 15;
    int tile = (gid >> 10) & 31;
    int ks   = (gid >> 6) & 15;
    int lane = gid & 63;
    const float* W = m ? Wc : Wq;
    int col = tile * 16 + (lane & 15);
    int k0  = ks * 32 + (lane >> 4) * 8;
    unsigned short* dst = wf + (size_t)gid * 8;
#pragma unroll
    for (int j = 0; j < 8; ++j)
        dst[j] = f2bf(W[(size_t)(k0 + j) * DIM + col]);
}

// ====================== Fused kernel: one block = one batch b ======================
// 512 threads, 8 waves = 8 heads. Phases:
//   1. stage query[b] AND context[b] tiles (64x512 f32) -> bf16 LDS, all 32
//      loads/thread hoisted (256KB/CU in flight), R12's verified zero-conflict
//      XOR swizzle: write slot (p*512 + (cw>>2)*256 + (cw&3)*64 + row) ^ cw,
//      read slot (p*512 + kk*256 + l4*64 + mt*16+l15) ^ (4*kk+l4) — same key
//      per element (cw = 4*kk_w + q_w, read q-pos = l4).
//   2. GEMM-C (16 K-steps from C-region, 64-AGPR acc) -> barrier ->
//      Cp+bias -> per-wave tail tile T (carved from the now-dead C region),
//      cb frags to regs.
//   3. GEMM-Q reusing the SAME acc from Q-region; Qp+bias -> T; qa/qb frags.
//   4. R3-proven in-register tail: Sc, both softmaxes, two outputs -> global.
// No pp intermediate: total HBM = 256MB acts + 268MB out + weights.
// Sequential GEMMs keep peak live regs ~<200 (stage-phase 128 regs have a
// disjoint lifetime). NOTE: plain __launch_bounds__ — a min-waves 2nd arg
// clamps the unified VGPR/AGPR budget below the accumulator -> spills
// (proved rounds 2 and 7).
__global__ __launch_bounds__(512) void fused_b(
    const float* __restrict__ query,
    const float* __restrict__ context,
    const float* __restrict__ bq,
    const float* __restrict__ bc,
    const unsigned short* __restrict__ wf,
    float* __restrict__ out)
{
    // 139264 B total: Q-stage 32768 shorts (64KB) + region2 36864 shorts
    // (72KB: C-stage uses first 64KB; 8 per-wave 64x72 tail tiles use all of it)
    __shared__ unsigned short smem[69632];
    unsigned short* Q = smem;
    unsigned short* C = smem + 32768;

    const int tid  = threadIdx.x;
    const int lane = tid & 63;
    const int wv   = tid >> 6;          // wave id = head
    const int l15  = lane & 15;
    const int l4   = lane >> 4;
    const int b    = blockIdx.x;

    const float* gq = query   + (size_t)b * SEQ * DIM;
    const float* gc = context + (size_t)b * SEQ * DIM;

    // ---------------- Phase 1: stage both tiles ----------------
    {
        const int row = tid >> 3;
        const int cw  = tid & 7;
        const int wsb = (cw >> 2) * 256 + (cw & 3) * 64 + row;
        const float* sq = gq + (size_t)row * DIM + cw * 8;
        const float* sc = gc + (size_t)row * DIM + cw * 8;
        float4 lq[16], lc[16];
#pragma unroll
        for (int p = 0; p < 8; ++p) {
            lq[2 * p]     = *(const float4*)(sq + p * 64);
            lq[2 * p + 1] = *(const float4*)(sq + p * 64 + 4);
        }
#pragma unroll
        for (int p = 0; p < 8; ++p) {
            lc[2 * p]     = *(const float4*)(sc + p * 64);
            lc[2 * p + 1] = *(const float4*)(sc + p * 64 + 4);
        }
#pragma unroll
        for (int p = 0; p < 8; ++p) {
            *(s16x8*)&Q[((p * 512 + wsb) ^ cw) * 8] = cvt2(lq[2 * p], lq[2 * p + 1]);
            *(s16x8*)&C[((p * 512 + wsb) ^ cw) * 8] = cvt2(lc[2 * p], lc[2 * p + 1]);
        }
    }
    __syncthreads();

    const f32x4 fz = {0.f, 0.f, 0.f, 0.f};
    f32x4 acc[4][4];

    // ---------------- Phase 2: GEMM-C ----------------
#pragma unroll
    for (int x = 0; x < 4; ++x)
#pragma unroll
        for (int y = 0; y < 4; ++y) acc[x][y] = fz;

    {
        const unsigned short* wfm = wf + 262144;   // Wc frags
#pragma unroll
        for (int ks = 0; ks < 16; ++ks) {
            const int p  = ks >> 1;
            const int kk = ks & 1;
            s16x8 af[4], bf[4];
#pragma unroll
            for (int mt = 0; mt < 4; ++mt) {
                const int s = p * 512 + kk * 256 + l4 * 64 + mt * 16 + l15;
                af[mt] = *(const s16x8*)&C[(s ^ (4 * kk + l4)) * 8];
            }
#pragma unroll
            for (int nt = 0; nt < 4; ++nt)
                bf[nt] = *(const s16x8*)(wfm +
                         ((size_t)((wv * 4 + nt) * 16 + ks) * 64 + lane) * 8);
#pragma unroll
            for (int mt = 0; mt < 4; ++mt)
#pragma unroll
                for (int nt = 0; nt < 4; ++nt)
                    acc[mt][nt] = mma(af[mt], bf[nt], acc[mt][nt]);
        }
    }
    __syncthreads();   // everyone done reading C-region before tail tiles land

    // per-wave 64x72 tail tile, carved from region2
    unsigned short (*T)[72] = (unsigned short(*)[72])(C + wv * 4608);

    // Cp + bias -> T ; cb frags (Cp^T as B operand: contiguous rows)
#pragma unroll
    for (int nt = 0; nt < 4; ++nt) {
        float bcv = bc[wv * 64 + nt * 16 + l15];
#pragma unroll
        for (int mt = 0; mt < 4; ++mt)
#pragma unroll
            for (int r = 0; r < 4; ++r)
                T[mt * 16 + l4 * 4 + r][nt * 16 + l15] = f2bf(acc[mt][nt][r] + bcv);
    }
    s16x8 cb[4][2];
#pragma unroll
    for (int nt = 0; nt < 4; ++nt)
#pragma unroll
        for (int ks = 0; ks < 2; ++ks)
            cb[nt][ks] = *(const s16x8*)&T[nt * 16 + l15][ks * 32 + l4 * 8];

    // ---------------- Phase 3: GEMM-Q (same acc regs) ----------------
#pragma unroll
    for (int x = 0; x < 4; ++x)
#pragma unroll
        for (int y = 0; y < 4; ++y) acc[x][y] = fz;

    {
#pragma unroll
        for (int ks = 0; ks < 16; ++ks) {
            const int p  = ks >> 1;
            const int kk = ks & 1;
            s16x8 af[4], bf[4];
#pragma unroll
            for (int mt = 0; mt < 4; ++mt) {
                const int s = p * 512 + kk * 256 + l4 * 64 + mt * 16 + l15;
                af[mt] = *(const s16x8*)&Q[(s ^ (4 * kk + l4)) * 8];
            }
#pragma unroll
            for (int nt = 0; nt < 4; ++nt)
                bf[nt] = *(const s16x8*)(wf +
                         ((size_t)((wv * 4 + nt) * 16 + ks) * 64 + lane) * 8);
#pragma unroll
            for (int mt = 0; mt < 4; ++mt)
#pragma unroll
                for (int nt = 0; nt < 4; ++nt)
                    acc[mt][nt] = mma(af[mt], bf[nt], acc[mt][nt]);
        }
    }

    // Qp + bias -> T (overwrites Cp; cb already in regs) ; qa/qb frags
#pragma unroll
    for (int nt = 0; nt < 4; ++nt) {
        float bqv = bq[wv * 64 + nt * 16 + l15];
#pragma unroll
        for (int mt = 0; mt < 4; ++mt)
#pragma unroll
            for (int r = 0; r < 4; ++r)
                T[mt * 16 + l4 * 4 + r][nt * 16 + l15] = f2bf(acc[mt][nt][r] + bqv);
    }
    s16x8 qa[4][2], qb[4][2];
#pragma unroll
    for (int mt = 0; mt < 4; ++mt)
#pragma unroll
        for (int ks = 0; ks < 2; ++ks)
            qa[mt][ks] = *(const s16x8*)&T[mt * 16 + l15][ks * 32 + l4 * 8];
#pragma unroll
    for (int nt = 0; nt < 4; ++nt)
#pragma unroll
        for (int ks = 0; ks < 2; ++ks) {
            s16x8 v;
#pragma unroll
            for (int j = 0; j < 8; ++j)
                v[j] = (short)T[ks * 32 + l4 * 8 + j][nt * 16 + l15];
            qb[nt][ks] = v;
        }

    // ---------------- Phase 4: attention tail (R3-proven) ----------------
    f32x4 Sc[4][4];
#pragma unroll
    for (int x = 0; x < 4; ++x)
#pragma unroll
        for (int y = 0; y < 4; ++y) Sc[x][y] = fz;
#pragma unroll
    for (int ks = 0; ks < 2; ++ks)
#pragma unroll
        for (int mt = 0; mt < 4; ++mt)
#pragma unroll
            for (int nt = 0; nt < 4; ++nt)
                Sc[mt][nt] = mma(qa[mt][ks], cb[nt][ks], Sc[mt][nt]);

    // softmax over keys (rows): P1 -> T
#pragma unroll
    for (int mt = 0; mt < 4; ++mt)
#pragma unroll
        for (int r = 0; r < 4; ++r) {
            float m = fmaxf(fmaxf(Sc[mt][0][r], Sc[mt][1][r]),
                            fmaxf(Sc[mt][2][r], Sc[mt][3][r]));
            m = fmaxf(m, __shfl_xor(m, 1));
            m = fmaxf(m, __shfl_xor(m, 2));
            m = fmaxf(m, __shfl_xor(m, 4));
            m = fmaxf(m, __shfl_xor(m, 8));
            float e[4], s = 0.f;
#pragma unroll
            for (int nt = 0; nt < 4; ++nt) { e[nt] = __expf(SCALE * (Sc[mt][nt][r] - m)); s += e[nt]; }
            s += __shfl_xor(s, 1);
            s += __shfl_xor(s, 2);
            s += __shfl_xor(s, 4);
            s += __shfl_xor(s, 8);
            float inv = 1.f / s;
            int row = mt * 16 + l4 * 4 + r;
#pragma unroll
            for (int nt = 0; nt < 4; ++nt)
                T[row][nt * 16 + l15] = f2bf(e[nt] * inv);
        }

    s16x8 pa[4][2];
#pragma unroll
    for (int mt = 0; mt < 4; ++mt)
#pragma unroll
        for (int ks = 0; ks < 2; ++ks)
            pa[mt][ks] = *(const s16x8*)&T[mt * 16 + l15][ks * 32 + l4 * 8];

    // softmax over queries (cols): P2^T -> T
#pragma unroll
    for (int nt = 0; nt < 4; ++nt) {
        float m = -1e30f;
#pragma unroll
        for (int mt = 0; mt < 4; ++mt)
#pragma unroll
            for (int r = 0; r < 4; ++r) m = fmaxf(m, Sc[mt][nt][r]);
        m = fmaxf(m, __shfl_xor(m, 16));
        m = fmaxf(m, __shfl_xor(m, 32));
        float ee[4][4], s = 0.f;
#pragma unroll
        for (int mt = 0; mt < 4; ++mt)
#pragma unroll
            for (int r = 0; r < 4; ++r) { ee[mt][r] = __expf(SCALE * (Sc[mt][nt][r] - m)); s += ee[mt][r]; }
        s += __shfl_xor(s, 16);
        s += __shfl_xor(s, 32);
        float inv = 1.f / s;
        int krow = nt * 16 + l15;
#pragma unroll
        for (int mt = 0; mt < 4; ++mt)
#pragma unroll
            for (int r = 0; r < 4; ++r)
                T[krow][mt * 16 + l4 * 4 + r] = f2bf(ee[mt][r] * inv);
    }

    // c_coattn = P1 @ Cp^T ; store
    f32x4 O[4][4];
#pragma unroll
    for (int x = 0; x < 4; ++x)
#pragma unroll
        for (int y = 0; y < 4; ++y) O[x][y] = fz;
#pragma unroll
    for (int ks = 0; ks < 2; ++ks)
#pragma unroll
        for (int mt = 0; mt < 4; ++mt)
#pragma unroll
            for (int nt = 0; nt < 4; ++nt)
                O[mt][nt] = mma(pa[mt][ks], cb[nt][ks], O[mt][nt]);

    float* cO = out;
#pragma unroll
    for (int mt = 0; mt < 4; ++mt)
#pragma unroll
        for (int nt = 0; nt < 4; ++nt)
#pragma unroll
            for (int r = 0; r < 4; ++r) {
                int qrow = mt * 16 + l4 * 4 + r;
                cO[((size_t)b * SEQ + qrow) * (NH * 64) + wv * 64 + nt * 16 + l15] = O[mt][nt][r];
            }

    // q_coattn = P2^T @ Qp ; store
    s16x8 p2a[4][2];
#pragma unroll
    for (int mt = 0; mt < 4; ++mt)
#pragma unroll
        for (int ks = 0; ks < 2; ++ks)
            p2a[mt][ks] = *(const s16x8*)&T[mt * 16 + l15][ks * 32 + l4 * 8];

#pragma unroll
    for (int x = 0; x < 4; ++x)
#pragma unroll
        for (int y = 0; y < 4; ++y) O[x][y] = fz;
#pragma unroll
    for (int ks = 0; ks < 2; ++ks)
#pragma unroll
        for (int mt = 0; mt < 4; ++mt)
#pragma unroll
            for (int nt = 0; nt < 4; ++nt)
                O[mt][nt] = mma(p2a[mt][ks], qb[nt][ks], O[mt][nt]);

    float* qO = out + (size_t)NB * SEQ * NH * 64;
#pragma unroll
    for (int mt = 0; mt < 4; ++mt)
#pragma unroll
        for (int nt = 0; nt < 4; ++nt)
#pragma unroll
            for (int r = 0; r < 4; ++r) {
                int krow = mt * 16 + l4 * 4 + r;
                qO[((size_t)b * SEQ + krow) * (NH * 64) + wv * 64 + nt * 16 + l15] = O[mt][nt][r];
            }
}

extern "C" void kernel_launch(void* const* d_in, const int* in_sizes, int n_in,
                              void* d_out, int out_size, void* d_ws, size_t ws_size,
                              hipStream_t stream) {
    const float* query   = (const float*)d_in[0];
    const float* context = (const float*)d_in[1];
    const float* Wq      = (const float*)d_in[2];
    const float* bq      = (const float*)d_in[3];
    const float* Wc      = (const float*)d_in[4];
    const float* bc      = (const float*)d_in[5];
    float* out = (float*)d_out;

    unsigned short* wfrag = (unsigned short*)d_ws;   // 1 MB bf16 weight frags

    prep_weights<<<256, 256, 0, stream>>>(Wq, Wc, wfrag);
    fused_b<<<NB, 512, 0, stream>>>(query, context, bq, bc, wfrag, out);
}